// Round 3
// baseline (169.558 us; speedup 1.0000x reference)
//
#include <hip/hip_runtime.h>
#include <cstdint>

#define PI_F 3.14159265358979323846f

__device__ __forceinline__ float fract_(float x)  { return __builtin_amdgcn_fractf(x); }
__device__ __forceinline__ float sin2pi_(float r) { return __builtin_amdgcn_sinf(r); }  // sin(2*pi*r)
__device__ __forceinline__ float cos2pi_(float r) { return __builtin_amdgcn_cosf(r); }  // cos(2*pi*r)

// ---------------------------------------------------------------------------
// Fused refiner, bit-exact restructure of the round-1 (passing) kernel.
//
// Round-1 arithmetic: S = ((a00+a01)+(a02+a03)) + ... folded as per-wave
// (a0+a1)+(a2+a3) then (S0+S1)+(S2+S3), where a(w,m) is a serial 16-step fma
// chain seeded at fract((64w+m)*crev), rotated by e^{i*2pi*4*crev}.
// Here: 8 waves, wave wv = 2*w_+h owns chains m = {2h, 2h+1} of group w_.
// Fold order preserved exactly -> bit-identical S, bit-identical trajectory.
// Only wave 0 maintains (u0,u1); it broadcasts {crev, C4, S4} (exact bits)
// through LDS. Sign bits are ballot-packed from global into LDS per block
// (no separate pack kernel, no workspace).
// ---------------------------------------------------------------------------
extern "C" __global__ void __launch_bounds__(512, 4)
refine_fused(const float* __restrict__ zr, const float* __restrict__ zi,
             const float* __restrict__ th0, const float* __restrict__ r0,
             const float* __restrict__ a_th_raw, const float* __restrict__ a_r_raw,
             const float* __restrict__ l_th_raw, const float* __restrict__ l_r_raw,
             float* __restrict__ out) {
    const int tid   = threadIdx.x;
    const int lane  = tid & 63;
    const int wv    = tid >> 6;            // wave 0..7
    const int item0 = blockIdx.x * 64;

    __shared__ uint32_t s_pr[64][9];       // [item][word], +1 pad (9*lane mod 32 spreads banks)
    __shared__ uint32_t s_pi[64][9];
    __shared__ float    s_b[3][64];        // crev, C4, S4 broadcast
    __shared__ float    s_red[8][64];      // per-wave partials

    // ---- pack phase: ballot-pack sign bits of this block's 64 items ----
    // wave wv, pass p covers elements item0*256 + p*512 + wv*64 + lane
    // -> item_local = 2p + (wv>>2), 64-bit k-window = wv&3. Coalesced dwords.
    {
        const int win  = wv & 3;
        const int iofs = wv >> 2;
        const size_t base = (size_t)item0 * 256 + (size_t)(wv * 64) + lane;
        #pragma unroll 4
        for (int p = 0; p < 32; ++p) {
            const float a = zr[base + (size_t)p * 512];
            const float b = zi[base + (size_t)p * 512];
            const unsigned long long ba = __ballot(a < 0.0f);
            const unsigned long long bb = __ballot(b < 0.0f);
            if (lane == 0) {
                const int it = 2 * p + iofs;
                s_pr[it][2 * win]     = (uint32_t)ba;
                s_pr[it][2 * win + 1] = (uint32_t)(ba >> 32);
                s_pi[it][2 * win]     = (uint32_t)bb;
                s_pi[it][2 * win + 1] = (uint32_t)(bb >> 32);
            }
        }
    }

    // ---- wave 0: initial u (verbatim round-1) ----
    float u0 = 0.0f, u1 = 0.0f;
    if (wv == 0) {
        const int item = item0 + lane;
        float y = th0[item] * (1.0f / 60.0f);
        y = fminf(fmaxf(y, -1.0f + 1e-6f), 1.0f - 1e-6f);
        u0 = atanhf(y);
        float sR = r0[item] * (1.0f / 2000.0f);
        sR = fminf(fmaxf(sR, 1e-6f), 1.0f - 1e-6f);
        u1 = atanhf(2.0f * sR - 1.0f);
    }
    __syncthreads();                        // pack done

    // this wave's 64-bit k-window (group w_) for item = lane
    const int w_ = wv >> 1;
    const uint32_t br0 = s_pr[lane][2 * w_];
    const uint32_t br1 = s_pr[lane][2 * w_ + 1];
    const uint32_t bi0 = s_pi[lane][2 * w_];
    const uint32_t bi1 = s_pi[lane][2 * w_ + 1];

    const float w64 = (float)(64 * w_);
    const int   mA  = 2 * (wv & 1);         // this wave's chains: mA, mA+1

    float T0 = 0.0f, T1 = 0.0f, cth = 0.0f; // wave-0 persistent head state

    for (int t = 0; t < 10; ++t) {
        // ---- head (wave 0 only, verbatim round-1 expressions) ----
        if (wv == 0) {
            T0 = tanhf(u0);
            T1 = tanhf(u1);
            const float th_rad = (PI_F / 3.0f) * T0;
            const float sth = sinf(th_rad);
            cth = cosf(th_rad);
            const float r    = 1000.0f * (T1 + 1.0f);
            const float crev = 0.5f * sth - 2e-4f * r;
            const float d4   = fract_(4.0f * crev);
            s_b[0][lane] = crev;
            s_b[1][lane] = cos2pi_(d4);
            s_b[2][lane] = sin2pi_(d4);
        }
        __syncthreads();                    // broadcast ready
        const float crev = s_b[0][lane];
        const float C4   = s_b[1][lane];
        const float S4   = s_b[2][lane];

        // ---- two chains, verbatim round-1 inner arithmetic ----
        float c[2], s[2], kf[2], acc[2];
        #pragma unroll
        for (int mm = 0; mm < 2; ++mm) {
            const float k0 = w64 + (float)(mA + mm);
            const float rv = fract_(k0 * crev);
            c[mm]   = cos2pi_(rv);
            s[mm]   = sin2pi_(rv);
            kf[mm]  = k0;
            acc[mm] = 0.0f;
        }

        #pragma unroll
        for (int j = 0; j < 16; ++j) {
            #pragma unroll
            for (int mm = 0; mm < 2; ++mm) {
                // kl = (mA+mm) + 4j in [0,64); word select is compile-time (j<8)
                const uint32_t wr = (j < 8) ? br0 : br1;
                const uint32_t wi = (j < 8) ? bi0 : bi1;
                const int sh = 31 - ((mA + mm + 4 * j) & 31);
                const uint32_t mre = (wr << sh) & 0x80000000u;
                const uint32_t mim = (wi << sh) & 0x80000000u;
                const float cs = c[mm], ss = s[mm];
                const float zc = __uint_as_float(__float_as_uint(cs) ^ mim); // z_im*cos
                const float zs = __uint_as_float(__float_as_uint(ss) ^ mre); // z_re*sin
                const float w0 = zc - zs;
                const float u2 = ss * ss;
                const float t2 = fmaf(-2.0f, u2, 1.0f);
                const float sc = ss * cs;
                const float v  = sc * t2;
                const float Wk = fmaf(v, -(1.0f / 196608.0f), w0 * 0.0625f);
                acc[mm] = fmaf(kf[mm], Wk, acc[mm]);
                kf[mm] += 4.0f;
                const float tA = ss * S4;
                const float tB = cs * S4;
                c[mm] = fmaf(cs, C4, -tA);
                s[mm] = fmaf(ss, C4, tB);
            }
        }

        // partial = round-1's (acc[2h] + acc[2h+1]) for group w_
        s_red[wv][lane] = acc[0] + acc[1];
        __syncthreads();                    // partials ready

        // ---- fold + update (wave 0 only, round-1 exact fold tree) ----
        if (wv == 0) {
            const float S0 = s_red[0][lane] + s_red[1][lane];   // wave-0 partial
            const float S1 = s_red[2][lane] + s_red[3][lane];   // wave-1 partial
            const float S2 = s_red[4][lane] + s_red[5][lane];   // wave-2 partial
            const float S3 = s_red[6][lane] + s_red[7][lane];   // wave-3 partial
            const float S  = (S0 + S1) + (S2 + S3);

            const float ath = fminf(fmaxf(log1pf(expf(a_th_raw[t])), 1e-6f), 0.2f);
            const float ar  = fminf(fmaxf(log1pf(expf(a_r_raw [t])), 1e-6f), 0.2f);
            const float lth = fminf(fmaxf(log1pf(expf(l_th_raw[t])), 1e-6f), 1.0f);
            const float lr  = fminf(fmaxf(log1pf(expf(l_r_raw [t])), 1e-6f), 1.0f);

            const float g0 = -(PI_F * PI_F / 3.0f) * cth * (1.0f - T0 * T0) * S;
            const float g1 = 0.4f * PI_F * (1.0f - T1 * T1) * S;
            const float den0 = fmaxf(fabsf(g0), 1e-6f) + lth;
            const float den1 = fmaxf(fabsf(g1), 1e-6f) + lr;
            float st0 = ath * g0 / den0;
            float st1 = ar  * g1 / den1;
            st0 = fminf(fmaxf(st0, -0.1f), 0.1f);
            st1 = fminf(fmaxf(st1, -0.1f), 0.1f);
            u0 -= st0;
            u1 -= st1;
        }
    }

    if (wv == 0) {
        const float thT = 60.0f * tanhf(u0);
        const float rT  = 1000.0f * (tanhf(u1) + 1.0f);
        reinterpret_cast<float2*>(out)[item0 + lane] = make_float2(thT, rT);
    }
}

extern "C" void kernel_launch(void* const* d_in, const int* in_sizes, int n_in,
                              void* d_out, int out_size, void* d_ws, size_t ws_size,
                              hipStream_t stream) {
    const float* zr   = (const float*)d_in[0];
    const float* zi   = (const float*)d_in[1];
    const float* th0  = (const float*)d_in[2];
    const float* r0   = (const float*)d_in[3];
    const float* athr = (const float*)d_in[4];
    const float* arr  = (const float*)d_in[5];
    const float* lthr = (const float*)d_in[6];
    const float* lrr  = (const float*)d_in[7];

    const int B = in_sizes[2];             // 32768 items

    refine_fused<<<B / 64, 512, 0, stream>>>(zr, zi, th0, r0, athr, arr, lthr, lrr,
                                             (float*)d_out);
}

// Round 4
// 139.065 us; speedup vs baseline: 1.2193x; 1.2193x over previous
//
#include <hip/hip_runtime.h>
#include <cstdint>

#define PI_F 3.14159265358979323846f

__device__ __forceinline__ float fract_(float x)  { return __builtin_amdgcn_fractf(x); }
__device__ __forceinline__ float sin2pi_(float r) { return __builtin_amdgcn_sinf(r); }  // sin(2*pi*r)
__device__ __forceinline__ float cos2pi_(float r) { return __builtin_amdgcn_cosf(r); }  // cos(2*pi*r)

// ---------------------------------------------------------------------------
// Kernel A: compress z_real/z_imag (+-1) to sign bitmasks, one 32-bit word
// per thread (bit j of word t = sign(z[32t+j]) < 0). 8 float4 loads per array
// per thread; each 128B line consumed entirely by one thread -> ideal 67 MB
// read + 2 MB write, fully latency-tolerant (1024 blocks).
// Bit layout identical to the round-1 ballot pack.
// ---------------------------------------------------------------------------
extern "C" __global__ void __launch_bounds__(256)
pack_signs(const float4* __restrict__ zr, const float4* __restrict__ zi,
           uint32_t* __restrict__ pr, uint32_t* __restrict__ pim) {
    const int t = blockIdx.x * 256 + threadIdx.x;     // word index
    uint32_t wr = 0u, wi = 0u;
    #pragma unroll
    for (int q = 0; q < 8; ++q) {
        const float4 a = zr[t * 8 + q];
        const float4 b = zi[t * 8 + q];
        wr |= ((uint32_t)(a.x < 0.f) << (4 * q))     | ((uint32_t)(a.y < 0.f) << (4 * q + 1))
            | ((uint32_t)(a.z < 0.f) << (4 * q + 2)) | ((uint32_t)(a.w < 0.f) << (4 * q + 3));
        wi |= ((uint32_t)(b.x < 0.f) << (4 * q))     | ((uint32_t)(b.y < 0.f) << (4 * q + 1))
            | ((uint32_t)(b.z < 0.f) << (4 * q + 2)) | ((uint32_t)(b.w < 0.f) << (4 * q + 3));
    }
    pr[t] = wr;
    pim[t] = wi;
}

// ---------------------------------------------------------------------------
// Kernel B: round-1 refiner VERBATIM in all FP-visible arithmetic
// (trajectory bit-identical -> absmax 36.0), with two bit-neutral changes:
//   * softplus params hoisted out of the t-loop (40 lanes compute all 40
//     values once, identical expression -> identical bits, LDS broadcast)
//   * parity double-buffered LDS reduction -> 1 barrier/iter instead of 2
// ---------------------------------------------------------------------------
extern "C" __global__ void __launch_bounds__(256)
refine(const float* __restrict__ th0, const float* __restrict__ r0,
       const float* __restrict__ a_th_raw, const float* __restrict__ a_r_raw,
       const float* __restrict__ l_th_raw, const float* __restrict__ l_r_raw,
       const uint32_t* __restrict__ pr, const uint32_t* __restrict__ pim,
       float* __restrict__ out) {
    const int lane = threadIdx.x & 63;
    const int w    = threadIdx.x >> 6;       // wave id 0..3, owns k in [w*64, w*64+64)
    const int item = blockIdx.x * 64 + lane;

    __shared__ float sp[4][10];              // ath, ar, lth, lr per step
    __shared__ float red[2][4][64];          // parity-double-buffered reduce

    if (threadIdx.x < 40) {
        const int a = threadIdx.x / 10, i = threadIdx.x % 10;
        const float* src = (a == 0) ? a_th_raw : (a == 1) ? a_r_raw
                         : (a == 2) ? l_th_raw : l_r_raw;
        const float v  = log1pf(expf(src[i]));           // verbatim round-1 expr
        const float hi = (a < 2) ? 0.2f : 1.0f;
        sp[a][i] = fminf(fmaxf(v, 1e-6f), hi);
    }

    // sign bits for this wave's 64 k's (2 words per component)
    const uint32_t br0 = pr [item * 8 + w * 2 + 0];
    const uint32_t br1 = pr [item * 8 + w * 2 + 1];
    const uint32_t bi0 = pim[item * 8 + w * 2 + 0];
    const uint32_t bi1 = pim[item * 8 + w * 2 + 1];

    // u0 = atanh(theta/60), u1 = atanh(2*(r/2000)-1), with reference clips
    float y = th0[item] * (1.0f / 60.0f);
    y = fminf(fmaxf(y, -1.0f + 1e-6f), 1.0f - 1e-6f);
    float u0 = atanhf(y);
    float sR = r0[item] * (1.0f / 2000.0f);
    sR = fminf(fmaxf(sR, 1e-6f), 1.0f - 1e-6f);
    float u1 = atanhf(2.0f * sR - 1.0f);

    const float w64 = (float)(w * 64);

    __syncthreads();                          // sp[] ready

    for (int t = 0; t < 10; ++t) {
        const float ath = sp[0][t], ar = sp[1][t], lth = sp[2][t], lr = sp[3][t];

        const float T0 = tanhf(u0), T1 = tanhf(u1);
        const float th_rad = (PI_F / 3.0f) * T0;          // 60*T0 deg -> rad
        const float sth = sinf(th_rad), cth = cosf(th_rad);
        const float r   = 1000.0f * (T1 + 1.0f);
        const float crev = 0.5f * sth - 2e-4f * r;        // revolutions per unit k

        // rotation step e^{i*2pi*4*crev}
        const float d4 = fract_(4.0f * crev);
        const float C4 = cos2pi_(d4), S4 = sin2pi_(d4);

        float c[4], s[4], kf[4], acc[4];
        #pragma unroll
        for (int m = 0; m < 4; ++m) {
            const float k0 = w64 + (float)m;
            const float rv = fract_(k0 * crev);
            c[m] = cos2pi_(rv);
            s[m] = sin2pi_(rv);
            kf[m]  = k0;
            acc[m] = 0.0f;
        }

        #pragma unroll
        for (int j = 0; j < 16; ++j) {
            #pragma unroll
            for (int m = 0; m < 4; ++m) {
                const int kl = m + 4 * j;                  // 0..63, compile-time
                const uint32_t wr = (kl < 32) ? br0 : br1;
                const uint32_t wi = (kl < 32) ? bi0 : bi1;
                const int sh = 31 - (kl & 31);
                const uint32_t mre = (wr << sh) & 0x80000000u;
                const uint32_t mim = (wi << sh) & 0x80000000u;
                const float cs = c[m], ss = s[m];
                const float zc = __uint_as_float(__float_as_uint(cs) ^ mim); // z_im*cos
                const float zs = __uint_as_float(__float_as_uint(ss) ^ mre); // z_re*sin
                const float w0 = zc - zs;
                // cubic sigma term: -sin(4phi)/786432 = -s*c*(1-2s^2)/196608
                const float u2 = ss * ss;
                const float t2 = fmaf(-2.0f, u2, 1.0f);
                const float sc = ss * cs;
                const float v  = sc * t2;
                const float W  = fmaf(v, -(1.0f / 196608.0f), w0 * 0.0625f);
                acc[m] = fmaf(kf[m], W, acc[m]);
                kf[m] += 4.0f;
                // rotate phase by 4*crev revolutions
                const float tA = ss * S4;
                const float tB = cs * S4;
                c[m] = fmaf(cs, C4, -tA);
                s[m] = fmaf(ss, C4, tB);
            }
        }
        float S = (acc[0] + acc[1]) + (acc[2] + acc[3]);

        // cross-wave reduce, parity double-buffered (WAR on buffer p=t&1 is
        // protected by the barrier of iteration t+1)
        const int p = t & 1;
        red[p][w][lane] = S;
        __syncthreads();
        S = (red[p][0][lane] + red[p][1][lane]) + (red[p][2][lane] + red[p][3][lane]);

        // gradient of -loglike wrt u, then normalized clipped step (verbatim)
        const float g0 = -(PI_F * PI_F / 3.0f) * cth * (1.0f - T0 * T0) * S;
        const float g1 = 0.4f * PI_F * (1.0f - T1 * T1) * S;
        const float den0 = fmaxf(fabsf(g0), 1e-6f) + lth;
        const float den1 = fmaxf(fabsf(g1), 1e-6f) + lr;
        float st0 = ath * g0 / den0;
        float st1 = ar  * g1 / den1;
        st0 = fminf(fmaxf(st0, -0.1f), 0.1f);
        st1 = fminf(fmaxf(st1, -0.1f), 0.1f);
        u0 -= st0;
        u1 -= st1;
    }

    if (w == 0) {
        const float thT = 60.0f * tanhf(u0);
        const float rT  = 1000.0f * (tanhf(u1) + 1.0f);
        reinterpret_cast<float2*>(out)[item] = make_float2(thT, rT);
    }
}

extern "C" void kernel_launch(void* const* d_in, const int* in_sizes, int n_in,
                              void* d_out, int out_size, void* d_ws, size_t ws_size,
                              hipStream_t stream) {
    const float* zr   = (const float*)d_in[0];
    const float* zi   = (const float*)d_in[1];
    const float* th0  = (const float*)d_in[2];
    const float* r0   = (const float*)d_in[3];
    const float* athr = (const float*)d_in[4];
    const float* arr  = (const float*)d_in[5];
    const float* lthr = (const float*)d_in[6];
    const float* lrr  = (const float*)d_in[7];

    const int B  = in_sizes[2];          // 32768
    const int BK = in_sizes[0];          // B*K = 8388608

    uint32_t* pr  = (uint32_t*)d_ws;     // B*8 words = 1 MB
    uint32_t* pim = pr + (size_t)B * 8;  // B*8 words = 1 MB

    pack_signs<<<(BK / 32) / 256, 256, 0, stream>>>((const float4*)zr, (const float4*)zi,
                                                    pr, pim);
    refine<<<B / 64, 256, 0, stream>>>(th0, r0, athr, arr, lthr, lrr, pr, pim,
                                       (float*)d_out);
}